// Round 6
// baseline (4971.786 us; speedup 1.0000x reference)
//
// LSTM_42030549958804 — fused 2-layer persistent bf16-MFMA LSTM, MI355X (gfx950)
//
// R10 = R9 (proven protocol, delegated polling) + global_load_lds cooperative
// tile staging (the next structural change).
//  - R9 post-mortem: poll congestion ruled out (512->128 pollers = -2%).
//    Remaining theory: VGPR-starved serialization of the 16-32 fresh-address
//    global loads per step (weights eat 96-128 of 124 VGPRs; loads fly in
//    small batches, each exposing ~0.5us LLC latency) + 4x per-WG redundant
//    tile loads (all waves read the same (t,g) tile).
//  - Fix: WG-cooperative __builtin_amdgcn_global_load_lds staging (0 VGPRs,
//    all loads concurrently in flight, one tile load per WG instead of four).
//    L0 additionally prefetches x(t+1) at step end (flies under store+flag+
//    poll), using counted vmcnt + raw s_barrier so the prefetch survives.
//  - ALL flag/poll/data-visibility semantics byte-identical to R9 (proven):
//    agent AS64 h stores + vmcnt(0) release, per-wave agent flags, delegated
//    agent AL32 polls + LDS epoch, AL64 h1-ring stage loads, plain reads at
//    fresh addresses. LDS tile WAR protected by the flag protocol + barriers.
//  - Fail-fast shared spin budgets kept: deadlock => <1s free-run, never a wedge.
// MFMA 16x16x32_bf16; A: m=lane&15,k=(lane>>4)*8+j; D: col=lane&15,row=(lane>>4)*4+reg.

#include <hip/hip_runtime.h>
#include <cstdint>
#include <cstddef>

#define B_  256
#define T_  512

typedef unsigned short u16;
typedef unsigned long long u64;
typedef __bf16 bf16x8 __attribute__((ext_vector_type(8)));
typedef float f32x4 __attribute__((ext_vector_type(4)));

#define AL32(p)   __hip_atomic_load((p),      __ATOMIC_RELAXED, __HIP_MEMORY_SCOPE_AGENT)
#define AL64(p)   __hip_atomic_load((p),      __ATOMIC_RELAXED, __HIP_MEMORY_SCOPE_AGENT)
#define AS32(p,v) __hip_atomic_store((p),(v), __ATOMIC_RELAXED, __HIP_MEMORY_SCOPE_AGENT)
#define AS64(p,v) __hip_atomic_store((p),(v), __ATOMIC_RELAXED, __HIP_MEMORY_SCOPE_AGENT)

__device__ __forceinline__ u16 f2bf(float x) {
  union { float f; unsigned int u; } v; v.f = x;
  unsigned int r = (v.u + 0x7fffu + ((v.u >> 16) & 1u)) >> 16;
  return (u16)r;
}
__device__ __forceinline__ float sigm(float x) { return 1.0f / (1.0f + __expf(-x)); }
__device__ __forceinline__ float tanh_(float x) {
  float e = __expf(2.0f * x);
  return 1.0f - 2.0f / (e + 1.0f);
}

// WG-cooperative tile stage: BYTES must be a multiple of 4096 (4 waves x 1KB).
// Per call r: wave w stages bytes [r*4096 + w*1024, +1024) -> LDS same offset.
// Uses NO VGPRs for data; tracked by vmcnt. Plain-cached load semantics
// (safe at fresh addresses — R4-proven pattern).
template<int BYTES>
__device__ __forceinline__ void stage_tile(const u16* __restrict__ g_, void* l_,
                                           int wave, int lane) {
  const char* gp = (const char*)g_ + wave * 1024 + lane * 16;
  char* lp = (char*)l_ + wave * 1024;
#pragma unroll
  for (int r = 0; r < BYTES; r += 4096) {
    __builtin_amdgcn_global_load_lds(
        (const __attribute__((address_space(1))) unsigned int*)(gp + r),
        (__attribute__((address_space(3))) unsigned int*)(lp + r), 16, 0, 0);
  }
}

// ---------------- group "barrier": 128 packed per-wave flags (R4-proven) ------
// Called by wave 0 only. budget shared across the whole loop: fail fast.
__device__ __forceinline__ void poll1(const unsigned int* f, unsigned int need,
                                      int lane, unsigned int& budget) {
  while (budget) {
    unsigned int a = AL32(f + lane);
    unsigned int b = AL32(f + 64 + lane);
    if (__all(a >= need && b >= need)) return;
    __builtin_amdgcn_s_sleep(1);
    --budget;
  }
}
// Waves 1-3: spin on the per-WG LDS epoch word (no fabric traffic, no vm drain).
__device__ __forceinline__ void lds_wait(volatile int* eps, int need,
                                         unsigned int& budget) {
  while (*eps < need && budget) {
    __builtin_amdgcn_s_sleep(1);
    --budget;
  }
}

// ---------------- weight pack: [Wih | Whh] -> fragment-ordered bf16 ----------------
template<int KXC>
__global__ void pack_w(const float* __restrict__ Wih, const float* __restrict__ Whh,
                       const float* __restrict__ bih, const float* __restrict__ bhh,
                       u16* __restrict__ Wp, float* __restrict__ bp)
{
  constexpr int KC = KXC + 16;
  constexpr int KX = KXC * 32;
  const int total = 2048 * KC * 4;          // 16B groups
  int gid = blockIdx.x * 256 + threadIdx.x;
  if (gid < 2048) {
    int gg = gid & 3, u = gid >> 2;
    bp[gid] = bih[gg * 512 + u] + bhh[gg * 512 + u];
  }
  if (gid >= total) return;
  int lane = gid & 63;
  int tmp  = gid >> 6;
  int kc   = tmp % KC;
  int c16  = tmp / KC;
  int pc   = c16 * 16 + (lane & 15);
  int k0   = kc * 32 + (lane >> 4) * 8;
  int gg = pc & 3, u = pc >> 2;
  int row = gg * 512 + u;
  union { u16 v[8]; uint4 q; } out;
#pragma unroll
  for (int j = 0; j < 8; ++j) {
    int k = k0 + j;
    float f = (k < KX) ? Wih[(size_t)row * KX + k] : Whh[(size_t)row * 512 + (k - KX)];
    out.v[j] = f2bf(f);
  }
  *(uint4*)(Wp + (size_t)gid * 8) = out.q;
}

// ---------------- X fp32 [B,T,I] -> bf16 fragment-ordered ----------------
__global__ void pack_x(const float* __restrict__ X, u16* __restrict__ Xp)
{
  int gid = blockIdx.x * 256 + threadIdx.x;  // total = 4194304, exact grid
  int lane = gid & 63;
  int tmp  = gid >> 6;
  int kc   = tmp & 7;
  int tmp2 = tmp >> 3;
  int b16  = tmp2 & 15;
  int t    = tmp2 >> 4;
  int b  = b16 * 16 + (lane & 15);
  int i0 = kc * 32 + (lane >> 4) * 8;
  const float* src = X + ((size_t)b * T_ + t) * 256 + i0;
  float4 f0 = *(const float4*)src;
  float4 f1 = *(const float4*)(src + 4);
  union { u16 v[8]; uint4 q; } out;
  out.v[0] = f2bf(f0.x); out.v[1] = f2bf(f0.y); out.v[2] = f2bf(f0.z); out.v[3] = f2bf(f0.w);
  out.v[4] = f2bf(f1.x); out.v[5] = f2bf(f1.y); out.v[6] = f2bf(f1.z); out.v[7] = f2bf(f1.w);
  *(uint4*)(Xp + (size_t)gid * 8) = out.q;
}

// ---------------- one layer's persistent loop (per wave) ----------------
// wave widx (0..127) of group g: units j = widx*4..widx*4+3, batch rows g*32..g*32+31.
// LDS tile layout in `big` (u64[8192] = 64KB):
//   L0: xlds 16KB @0 (x tile), hlds 32KB @16K (h0(t-1) tile)
//   L1: xlds 32KB @0 (h0(t) tile), hlds 32KB @32K (h1(t-1) tile, via AL64+ds_write)
template<int KXC, bool L1, bool LAST>
__device__ __forceinline__ void layer_loop(
    const u16* __restrict__ Wp, const float* __restrict__ bp,
    const u16* __restrict__ Xsrc, u16* __restrict__ Hdst,
    float* __restrict__ hlast,
    unsigned int* __restrict__ fown, const unsigned int* __restrict__ fprev,
    int g, int widx, int lane, int tid, int wave,
    float* gw, u16* hst, u64* big, volatile int* eps_a, volatile int* eps_b)
{
  constexpr int KC = KXC + 16;
  unsigned int budget = 1u << 22;           // shared across the whole loop
  // ---- weights -> registers ----
  bf16x8 wx[KXC], wh[16];
  const u16* wsrc = Wp + (size_t)widx * KC * 512 + lane * 8;
#pragma unroll
  for (int kc = 0; kc < KXC; ++kc) wx[kc] = *(const bf16x8*)(wsrc + kc * 512);
#pragma unroll
  for (int kc = 0; kc < 16; ++kc)  wh[kc] = *(const bf16x8*)(wsrc + (KXC + kc) * 512);

  const int uw = lane & 3, r0 = lane >> 2;      // pointwise ownership
  const int jb = widx * 4;
  const float4 bb = *(const float4*)(bp + (jb + uw) * 4);
  float c0 = 0.f, c1 = 0.f;
  const int kcb = widx >> 3, qq = (widx >> 1) & 3, jjb = (widx & 1) * 4;

  u16* xlds = (u16*)big;                       // x tile
  u16* hlds = (u16*)big + (L1 ? 16384 : 8192); // h tile
  u64* hbw  = big + 4096;                      // L1 h tile u64 view for ds_write

  // L0: pre-stage x(0) so the t=0 iteration only waits vmcnt(0).
  if (!L1) stage_tile<16384>(Xsrc + (size_t)(g * 2) * (KXC * 512), xlds, wave, lane);

  for (int t = 0; t < T_; ++t) {
    f32x4 acc0 = {0.f, 0.f, 0.f, 0.f};
    f32x4 acc1 = {0.f, 0.f, 0.f, 0.f};

    if (!L1) {
      // ---------------- layer 0 ----------------
      if (t > 0) {
        if (wave == 0) { poll1(fown, t, lane, budget); if (lane == 0) *eps_a = t; }
        else           lds_wait(eps_a, t, budget);
        asm volatile("" ::: "memory");
        // h0(t-1) tile -> LDS (8 issues). WAR safe: all waves flagged t.
        stage_tile<32768>(Hdst + (size_t)(t - 1) * 131072 + g * 16384, hlds, wave, lane);
        // <=8 outstanding => x(t) stages (older) + h store + flag all done.
        asm volatile("s_waitcnt vmcnt(8)" ::: "memory");
      } else {
        asm volatile("s_waitcnt vmcnt(0)" ::: "memory");
      }
      __builtin_amdgcn_s_barrier();            // all waves' x chunks landed
      asm volatile("" ::: "memory");
#pragma unroll
      for (int kc = 0; kc < KXC; ++kc) {
        bf16x8 a0 = *(const bf16x8*)(xlds + kc * 512 + lane * 8);
        bf16x8 a1 = *(const bf16x8*)(xlds + (KXC + kc) * 512 + lane * 8);
        acc0 = __builtin_amdgcn_mfma_f32_16x16x32_bf16(a0, wx[kc], acc0, 0, 0, 0);
        acc1 = __builtin_amdgcn_mfma_f32_16x16x32_bf16(a1, wx[kc], acc1, 0, 0, 0);
      }
      asm volatile("s_waitcnt vmcnt(0)" ::: "memory");
      __builtin_amdgcn_s_barrier();            // all waves' h chunks landed
      asm volatile("" ::: "memory");
      if (t > 0) {
#pragma unroll
        for (int kc = 0; kc < 16; ++kc) {
          bf16x8 a0 = *(const bf16x8*)(hlds + kc * 512 + lane * 8);
          bf16x8 a1 = *(const bf16x8*)(hlds + 8192 + kc * 512 + lane * 8);
          acc0 = __builtin_amdgcn_mfma_f32_16x16x32_bf16(a0, wh[kc], acc0, 0, 0, 0);
          acc1 = __builtin_amdgcn_mfma_f32_16x16x32_bf16(a1, wh[kc], acc1, 0, 0, 0);
        }
      }
    } else {
      // ---------------- layer 1 ----------------
      if (t > 0) {
        if (wave == 0) { poll1(fown, (unsigned)t, lane, budget); if (lane == 0) *eps_a = t; }
        else           lds_wait(eps_a, t, budget);
        asm volatile("" ::: "memory");
      }
      // own-h1 ring stage loads issued EARLY: latency hides under fprev wait.
      u64 stg[16];
      if (t > 0) {
        const u64* src = (const u64*)(Hdst + (size_t)((t - 1) & 3) * 131072 + g * 16384);
#pragma unroll
        for (int i = 0; i < 16; ++i) stg[i] = AL64(src + i * 256 + tid);
      }
      if (wave == 0) { poll1(fprev, (unsigned)(t + 1), lane, budget); if (lane == 0) *eps_b = t + 1; }
      else           lds_wait(eps_b, t + 1, budget);
      asm volatile("" ::: "memory");
      // h0(t) tile -> LDS (8 issues, fresh addresses)
      stage_tile<32768>(Xsrc + ((size_t)t * 16 + g * 2) * (KXC * 512), xlds, wave, lane);
      if (t > 0) {
#pragma unroll
        for (int i = 0; i < 16; ++i) hbw[i * 256 + tid] = stg[i];
      }
      asm volatile("s_waitcnt vmcnt(0) lgkmcnt(0)" ::: "memory");
      __builtin_amdgcn_s_barrier();            // x tile + h1 writes visible WG-wide
      asm volatile("" ::: "memory");
#pragma unroll
      for (int kc = 0; kc < KXC; ++kc) {
        bf16x8 a0 = *(const bf16x8*)(xlds + kc * 512 + lane * 8);
        bf16x8 a1 = *(const bf16x8*)(xlds + (KXC + kc) * 512 + lane * 8);
        acc0 = __builtin_amdgcn_mfma_f32_16x16x32_bf16(a0, wx[kc], acc0, 0, 0, 0);
        acc1 = __builtin_amdgcn_mfma_f32_16x16x32_bf16(a1, wx[kc], acc1, 0, 0, 0);
      }
      if (t > 0) {
#pragma unroll
        for (int kc = 0; kc < 16; ++kc) {
          bf16x8 a0 = *(const bf16x8*)(hlds + kc * 512 + lane * 8);
          bf16x8 a1 = *(const bf16x8*)(hlds + 8192 + kc * 512 + lane * 8);
          acc0 = __builtin_amdgcn_mfma_f32_16x16x32_bf16(a0, wh[kc], acc0, 0, 0, 0);
          acc1 = __builtin_amdgcn_mfma_f32_16x16x32_bf16(a1, wh[kc], acc1, 0, 0, 0);
        }
      }
    }

    // ---- per-wave epilogue: D-frag -> gw transpose (intra-wave, lgkm only) ----
    {
      int c = lane & 15, rr = (lane >> 4) * 4;
#pragma unroll
      for (int r = 0; r < 4; ++r) {
        gw[(rr + r) * 20 + c]      = acc0[r];
        gw[(rr + r + 16) * 20 + c] = acc1[r];
      }
    }
    float4 g0 = *(const float4*)(gw + r0 * 20 + uw * 4);
    float4 g1 = *(const float4*)(gw + (r0 + 16) * 20 + uw * 4);
    float hh0, hh1;
    {
      float ii = sigm(g0.x + bb.x), ff = sigm(g0.y + bb.y);
      float gg = tanh_(g0.z + bb.z), oo = sigm(g0.w + bb.w);
      c0 = ff * c0 + ii * gg; hh0 = oo * tanh_(c0);
      ii = sigm(g1.x + bb.x); ff = sigm(g1.y + bb.y);
      gg = tanh_(g1.z + bb.z); oo = sigm(g1.w + bb.w);
      c1 = ff * c1 + ii * gg; hh1 = oo * tanh_(c1);
    }
    hst[r0 * 4 + uw]        = f2bf(hh0);
    hst[(r0 + 16) * 4 + uw] = f2bf(hh1);
    if (LAST && t == T_ - 1) {
      hlast[(size_t)(g * 32 + r0) * 512 + (jb + uw)]      = hh0;
      hlast[(size_t)(g * 32 + r0 + 16) * 512 + (jb + uw)] = hh1;
    }
    // lane<32: one 8B write-through store (row = lane, 4 units contiguous)
    if (lane < 32) {
      int b16l = lane >> 4, bl = lane & 15;
      size_t off = (size_t)(L1 ? (t & 3) : t) * 131072
                 + (size_t)((g * 2 + b16l) * 16 + kcb) * 512 + (qq * 16 + bl) * 8 + jjb;
      u64 v = *(const u64*)(hst + lane * 4);
      AS64((u64*)(Hdst + off), v);
    }
    // L0: prefetch x(t+1) now — it flies under store-ack + flag + next poll.
    // Safe: all waves passed barrier #2 (x-part reads of xlds done).
    if (!L1 && t + 1 < T_) {
      stage_tile<16384>(Xsrc + ((size_t)(t + 1) * 16 + g * 2) * (KXC * 512), xlds, wave, lane);
      // <=4 outstanding = only the 4 prefetch issues => h store (older) done.
      asm volatile("s_waitcnt vmcnt(4)" ::: "memory");
    } else {
      asm volatile("s_waitcnt vmcnt(0)" ::: "memory");   // h at LLC before flag
    }
    if (lane == 0) AS32(fown + widx, (unsigned int)(t + 1));
    // LDS WAR across steps is protected by the flag protocol: any wave enters
    // step t+1 only after ALL group waves flagged t+1 (reads of step t done).
  }
}

__global__ __launch_bounds__(256, 2) void lstm_fused(
    const u16* __restrict__ Wp0, const float* __restrict__ bp0,
    const u16* __restrict__ Wp1, const float* __restrict__ bp1,
    const u16* __restrict__ Xsw, u16* __restrict__ Hrot0,
    u16* __restrict__ Hring, float* __restrict__ hlast,
    unsigned int* __restrict__ sync)
{
  __shared__ __align__(16) u64 big[8192];       // 64KB tile staging (see layout)
  __shared__ __align__(16) float gwb[4][640];   // per-wave gate transpose (stride 20)
  __shared__ u64 hstb[4][32];                   // per-wave h staging (256B)
  __shared__ int eps_a, eps_b;                  // per-WG step epochs (delegated poll)
  const int tid = threadIdx.x, lane = tid & 63, wave = tid >> 6;
  const int bid = blockIdx.x;
  if (tid == 0) { eps_a = 0; eps_b = 0; }
  __syncthreads();
  float* gw = gwb[wave];
  u16*  hst = (u16*)hstb[wave];
  if (bid < 256) {
    const int g = bid & 7, widx = (bid >> 3) * 4 + wave;
    layer_loop<8, false, false>(Wp0, bp0, Xsw, Hrot0, nullptr,
                                sync + g * 128, nullptr,
                                g, widx, lane, tid, wave, gw, hst, big, &eps_a, &eps_b);
  } else {
    const int b2 = bid - 256;
    const int g = b2 & 7, widx = (b2 >> 3) * 4 + wave;
    layer_loop<16, true, true>(Wp1, bp1, Hrot0, Hring, hlast,
                               sync + 1024 + g * 128, sync + g * 128,
                               g, widx, lane, tid, wave, gw, hst, big, &eps_a, &eps_b);
  }
}

// ---------------- final projection y = hlast @ Wlin^T + b ----------------
__global__ void final_k(const float* __restrict__ hlast, const float* __restrict__ Wlin,
                        const float* __restrict__ blin, float* __restrict__ out)
{
  int b = blockIdx.x;
  int l = threadIdx.x;  // 64
  float s = 0.f;
#pragma unroll
  for (int j = l; j < 512; j += 64) s += hlast[(size_t)b * 512 + j] * Wlin[j];
#pragma unroll
  for (int off = 32; off > 0; off >>= 1) s += __shfl_down(s, off);
  if (l == 0) out[b] = s + blin[0];
}

extern "C" void kernel_launch(void* const* d_in, const int* in_sizes, int n_in,
                              void* d_out, int out_size, void* d_ws, size_t ws_size,
                              hipStream_t stream) {
  (void)in_sizes; (void)n_in; (void)out_size; (void)ws_size;
  const float* X    = (const float*)d_in[0];
  const float* Wih0 = (const float*)d_in[1];
  const float* Whh0 = (const float*)d_in[2];
  const float* bih0 = (const float*)d_in[3];
  const float* bhh0 = (const float*)d_in[4];
  const float* Wih1 = (const float*)d_in[5];
  const float* Whh1 = (const float*)d_in[6];
  const float* bih1 = (const float*)d_in[7];
  const float* bhh1 = (const float*)d_in[8];
  const float* Wlin = (const float*)d_in[9];
  const float* blin = (const float*)d_in[10];
  float* out = (float*)d_out;

  char* ws = (char*)d_ws;
  size_t o = 0;
  auto take = [&](size_t bytes) { char* p = ws + o; o = (o + bytes + 255) & ~(size_t)255; return p; };
  u16*   Wp0   = (u16*)take(2048ull * 768 * 2);              // 3 MB
  u16*   Wp1   = (u16*)take(2048ull * 1024 * 2);             // 4 MB
  float* bp0   = (float*)take(2048 * 4);
  float* bp1   = (float*)take(2048 * 4);
  u16*   Xsw   = (u16*)take((size_t)B_ * T_ * 256 * 2);      // 67 MB
  u16*   Hrot0 = (u16*)take((size_t)T_ * B_ * 512 * 2);      // 134 MB (full-depth h0)
  u16*   Hring = (u16*)take((size_t)4 * B_ * 512 * 2);       // 1 MB (h1, depth 4)
  float* hlast = (float*)take((size_t)B_ * 512 * 4);         // 512 KB
  unsigned int* sync = (unsigned int*)take(8192);            // 2 layers x 8 groups x 128 flags

  hipMemsetAsync(sync, 0, 8192, stream);

  pack_w<8> <<<768,  256, 0, stream>>>(Wih0, Whh0, bih0, bhh0, Wp0, bp0);
  pack_w<16><<<1024, 256, 0, stream>>>(Wih1, Whh1, bih1, bhh1, Wp1, bp1);
  pack_x    <<<16384,256, 0, stream>>>(X, Xsw);

  lstm_fused<<<512, 256, 0, stream>>>(Wp0, bp0, Wp1, bp1, Xsw, Hrot0, Hring, hlast, sync);
  final_k<<<256, 64, 0, stream>>>(hlast, Wlin, blin, out);
}

// Round 7
// 3521.223 us; speedup vs baseline: 1.4119x; 1.4119x over previous
//
// LSTM_42030549958804 — fused 2-layer persistent bf16-MFMA LSTM, MI355X (gfx950)
//
// R11 = R9 (proven protocol, delegated polling) + flag-line DE-HOTSPOTTING.
//  - R9 (poll-read congestion) and R10 (load serialization / redundant tile
//    loads) were both nulls: step period pinned at ~9.3us. Remaining scaler:
//    128 per-wave flag STORES per group-layer-step all hitting the SAME 2
//    cache lines; memory-side LLC serializes same-line writes (~60-100ns
//    turnaround) => ~4-6us/step of pure flag-write serialization.
//  - Fix (one mechanism):
//     (1) per-WG flags: h-store -> vmcnt(0) -> __syncthreads -> tid0 stores
//         ONE flag. 128 -> 32 stores per group-layer-step.
//     (2) 128B-padded flags: each WG's flag on its OWN line. Same-line write
//         serialization 64 -> 1.
//     (3) poll: lane i reads WG i's line (lane<32: own/fown, lane>=32: fprev),
//         one load per lane per iteration, __all() combine. Delegated to
//         wave0 + LDS epoch broadcast (R9-proven).
//  - ALL memory-op semantics unchanged from R9 (proven): agent AS64 h stores,
//    agent AS32 flag stores, agent AL32 polls, AL64 h1-ring stage loads,
//    plain cached reads at fresh addresses. Ordering: flag(t+1) => whole WG
//    passed post-vmcnt(0) barrier => its h is at the coherence point.
//  - Fail-fast shared spin budgets kept: deadlock => <1s free-run, no wedge.
// MFMA 16x16x32_bf16; A: m=lane&15,k=(lane>>4)*8+j; D: col=lane&15,row=(lane>>4)*4+reg.

#include <hip/hip_runtime.h>
#include <cstdint>
#include <cstddef>

#define B_  256
#define T_  512

typedef unsigned short u16;
typedef unsigned long long u64;
typedef __bf16 bf16x8 __attribute__((ext_vector_type(8)));
typedef float f32x4 __attribute__((ext_vector_type(4)));

#define AL32(p)   __hip_atomic_load((p),      __ATOMIC_RELAXED, __HIP_MEMORY_SCOPE_AGENT)
#define AL64(p)   __hip_atomic_load((p),      __ATOMIC_RELAXED, __HIP_MEMORY_SCOPE_AGENT)
#define AS32(p,v) __hip_atomic_store((p),(v), __ATOMIC_RELAXED, __HIP_MEMORY_SCOPE_AGENT)
#define AS64(p,v) __hip_atomic_store((p),(v), __ATOMIC_RELAXED, __HIP_MEMORY_SCOPE_AGENT)

__device__ __forceinline__ u16 f2bf(float x) {
  union { float f; unsigned int u; } v; v.f = x;
  unsigned int r = (v.u + 0x7fffu + ((v.u >> 16) & 1u)) >> 16;
  return (u16)r;
}
__device__ __forceinline__ float sigm(float x) { return 1.0f / (1.0f + __expf(-x)); }
__device__ __forceinline__ float tanh_(float x) {
  float e = __expf(2.0f * x);
  return 1.0f - 2.0f / (e + 1.0f);
}

// ---------------- group "barrier": 32 per-WG flags, 128B apart ---------------
// Flag for WG w of a group-layer lives at f[w*32] (u32 stride 32 = 128B).
// Called by wave 0 only; budget shared across the whole loop: fail fast.
__device__ __forceinline__ void poll1(const unsigned int* f, unsigned int need,
                                      int lane, unsigned int& budget) {
  const unsigned int* p = f + (lane & 31) * 32;   // lanes 32-63 duplicate 0-31
  while (budget) {
    unsigned int a = AL32(p);
    if (__all(a >= need)) return;
    __builtin_amdgcn_s_sleep(1);
    --budget;
  }
}
// Dual poll in ONE load/lane/iter: lane<32 -> fp (need np), lane>=32 -> fo (need no).
__device__ __forceinline__ void poll2(const unsigned int* fp, unsigned int np,
                                      const unsigned int* fo, unsigned int no,
                                      int lane, unsigned int& budget) {
  const unsigned int* p = (lane < 32) ? (fp + lane * 32) : (fo + (lane - 32) * 32);
  const unsigned int nd = (lane < 32) ? np : no;
  while (budget) {
    unsigned int a = AL32(p);
    if (__all(a >= nd)) return;
    __builtin_amdgcn_s_sleep(1);
    --budget;
  }
}
// Waves 1-3: spin on the per-WG LDS epoch word (no fabric traffic).
__device__ __forceinline__ void lds_wait(volatile int* eps, int need,
                                         unsigned int& budget) {
  while (*eps < need && budget) {
    __builtin_amdgcn_s_sleep(1);
    --budget;
  }
}

// ---------------- weight pack: [Wih | Whh] -> fragment-ordered bf16 ----------------
template<int KXC>
__global__ void pack_w(const float* __restrict__ Wih, const float* __restrict__ Whh,
                       const float* __restrict__ bih, const float* __restrict__ bhh,
                       u16* __restrict__ Wp, float* __restrict__ bp)
{
  constexpr int KC = KXC + 16;
  constexpr int KX = KXC * 32;
  const int total = 2048 * KC * 4;          // 16B groups
  int gid = blockIdx.x * 256 + threadIdx.x;
  if (gid < 2048) {
    int gg = gid & 3, u = gid >> 2;
    bp[gid] = bih[gg * 512 + u] + bhh[gg * 512 + u];
  }
  if (gid >= total) return;
  int lane = gid & 63;
  int tmp  = gid >> 6;
  int kc   = tmp % KC;
  int c16  = tmp / KC;
  int pc   = c16 * 16 + (lane & 15);
  int k0   = kc * 32 + (lane >> 4) * 8;
  int gg = pc & 3, u = pc >> 2;
  int row = gg * 512 + u;
  union { u16 v[8]; uint4 q; } out;
#pragma unroll
  for (int j = 0; j < 8; ++j) {
    int k = k0 + j;
    float f = (k < KX) ? Wih[(size_t)row * KX + k] : Whh[(size_t)row * 512 + (k - KX)];
    out.v[j] = f2bf(f);
  }
  *(uint4*)(Wp + (size_t)gid * 8) = out.q;
}

// ---------------- X fp32 [B,T,I] -> bf16 fragment-ordered ----------------
__global__ void pack_x(const float* __restrict__ X, u16* __restrict__ Xp)
{
  int gid = blockIdx.x * 256 + threadIdx.x;  // total = 4194304, exact grid
  int lane = gid & 63;
  int tmp  = gid >> 6;
  int kc   = tmp & 7;
  int tmp2 = tmp >> 3;
  int b16  = tmp2 & 15;
  int t    = tmp2 >> 4;
  int b  = b16 * 16 + (lane & 15);
  int i0 = kc * 32 + (lane >> 4) * 8;
  const float* src = X + ((size_t)b * T_ + t) * 256 + i0;
  float4 f0 = *(const float4*)src;
  float4 f1 = *(const float4*)(src + 4);
  union { u16 v[8]; uint4 q; } out;
  out.v[0] = f2bf(f0.x); out.v[1] = f2bf(f0.y); out.v[2] = f2bf(f0.z); out.v[3] = f2bf(f0.w);
  out.v[4] = f2bf(f1.x); out.v[5] = f2bf(f1.y); out.v[6] = f2bf(f1.z); out.v[7] = f2bf(f1.w);
  *(uint4*)(Xp + (size_t)gid * 8) = out.q;
}

// ---------------- one layer's persistent loop (per wave) ----------------
// wave widx (0..127) of group g: units j = widx*4..widx*4+3, batch rows g*32..g*32+31.
// wgi = widx>>2 = WG index within group (0..31).
template<int KXC, bool L1, bool LAST>
__device__ __forceinline__ void layer_loop(
    const u16* __restrict__ Wp, const float* __restrict__ bp,
    const u16* __restrict__ Xsrc, u16* __restrict__ Hdst,
    float* __restrict__ hlast,
    unsigned int* __restrict__ fown, const unsigned int* __restrict__ fprev,
    int g, int widx, int lane, int tid, int wave,
    float* gw, u16* hst, u64* hbuf, volatile int* eps)
{
  constexpr int KC = KXC + 16;
  const int wgi = widx >> 2;
  unsigned int budget = 1u << 22;           // shared across the whole loop
  // ---- weights -> registers ----
  bf16x8 wx[KXC], wh[16];
  const u16* wsrc = Wp + (size_t)widx * KC * 512 + lane * 8;
#pragma unroll
  for (int kc = 0; kc < KXC; ++kc) wx[kc] = *(const bf16x8*)(wsrc + kc * 512);
#pragma unroll
  for (int kc = 0; kc < 16; ++kc)  wh[kc] = *(const bf16x8*)(wsrc + (KXC + kc) * 512);

  const int uw = lane & 3, r0 = lane >> 2;      // pointwise ownership
  const int jb = widx * 4;
  const float4 bb = *(const float4*)(bp + (jb + uw) * 4);
  float c0 = 0.f, c1 = 0.f;
  const int kcb = widx >> 3, qq = (widx >> 1) & 3, jjb = (widx & 1) * 4;

  for (int t = 0; t < T_; ++t) {
    f32x4 acc0 = {0.f, 0.f, 0.f, 0.f};
    f32x4 acc1 = {0.f, 0.f, 0.f, 0.f};
    const u16* xs = Xsrc + ((size_t)t * 16 + g * 2) * (KXC * 512) + lane * 8;
    const int slot_r = L1 ? ((t - 1) & 3) : (t - 1);

    if (L1) {
      // h0(t) ready AND own group's h1(t-1): wave0 polls, broadcasts via LDS.
      if (wave == 0) {
        poll2(fprev, t + 1, fown, t, lane, budget);
        if (lane == 0) *eps = t + 1;
      } else {
        lds_wait(eps, t + 1, budget);
      }
      asm volatile("" ::: "memory");
    }

    // L1: issue own-h1 stage loads (agent ring loads — R4-proven)
    u64 stg[16];
    if (L1 && t > 0) {
      const u64* src = (const u64*)(Hdst + (size_t)slot_r * 131072 + g * 16384);
#pragma unroll
      for (int i = 0; i < 16; ++i) stg[i] = AL64(src + i * 256 + tid);
    }

    // ---- x-part (layer0: Xsw; layer1: h0(t) from Hrot0, plain cached) ----
#pragma unroll
    for (int kc = 0; kc < KXC; ++kc) {
      bf16x8 a0 = *(const bf16x8*)(xs + kc * 512);
      bf16x8 a1 = *(const bf16x8*)(xs + (KXC + kc) * 512);
      acc0 = __builtin_amdgcn_mfma_f32_16x16x32_bf16(a0, wx[kc], acc0, 0, 0, 0);
      acc1 = __builtin_amdgcn_mfma_f32_16x16x32_bf16(a1, wx[kc], acc1, 0, 0, 0);
    }

    if (!L1 && t > 0) {
      // own group's h(t-1): wave0 polls, broadcasts epoch t; waves 1-3 spin.
      if (wave == 0) {
        poll1(fown, t, lane, budget);
        if (lane == 0) *eps = t;
      } else {
        lds_wait(eps, t, budget);
      }
      asm volatile("" ::: "memory");
    }

    // ---- h-part ----
    if (t > 0) {
      if (!L1) {
        // fresh full-depth slots: plain cached b128 loads (R4-proven)
        const u16* hs = Hdst + (size_t)slot_r * 131072 + g * 16384 + lane * 8;
#pragma unroll
        for (int kc = 0; kc < 16; ++kc) {
          bf16x8 a0 = *(const bf16x8*)(hs + kc * 512);
          bf16x8 a1 = *(const bf16x8*)(hs + 8192 + kc * 512);
          acc0 = __builtin_amdgcn_mfma_f32_16x16x32_bf16(a0, wh[kc], acc0, 0, 0, 0);
          acc1 = __builtin_amdgcn_mfma_f32_16x16x32_bf16(a1, wh[kc], acc1, 0, 0, 0);
        }
      } else {
        // staged tile -> LDS (WG-coop, cuts agent-load LLC traffic 4x)
#pragma unroll
        for (int i = 0; i < 16; ++i) hbuf[i * 256 + tid] = stg[i];
        __syncthreads();
        const u16* hs = (const u16*)hbuf + lane * 8;
#pragma unroll
        for (int kc = 0; kc < 16; ++kc) {
          bf16x8 a0 = *(const bf16x8*)(hs + kc * 512);
          bf16x8 a1 = *(const bf16x8*)(hs + 8192 + kc * 512);
          acc0 = __builtin_amdgcn_mfma_f32_16x16x32_bf16(a0, wh[kc], acc0, 0, 0, 0);
          acc1 = __builtin_amdgcn_mfma_f32_16x16x32_bf16(a1, wh[kc], acc1, 0, 0, 0);
        }
      }
    }

    // ---- per-wave epilogue: D-frag -> gw transpose (intra-wave, lgkm only) ----
    {
      int c = lane & 15, rr = (lane >> 4) * 4;
#pragma unroll
      for (int r = 0; r < 4; ++r) {
        gw[(rr + r) * 20 + c]      = acc0[r];
        gw[(rr + r + 16) * 20 + c] = acc1[r];
      }
    }
    float4 g0 = *(const float4*)(gw + r0 * 20 + uw * 4);
    float4 g1 = *(const float4*)(gw + (r0 + 16) * 20 + uw * 4);
    float hh0, hh1;
    {
      float ii = sigm(g0.x + bb.x), ff = sigm(g0.y + bb.y);
      float gg = tanh_(g0.z + bb.z), oo = sigm(g0.w + bb.w);
      c0 = ff * c0 + ii * gg; hh0 = oo * tanh_(c0);
      ii = sigm(g1.x + bb.x); ff = sigm(g1.y + bb.y);
      gg = tanh_(g1.z + bb.z); oo = sigm(g1.w + bb.w);
      c1 = ff * c1 + ii * gg; hh1 = oo * tanh_(c1);
    }
    hst[r0 * 4 + uw]        = f2bf(hh0);
    hst[(r0 + 16) * 4 + uw] = f2bf(hh1);
    if (LAST && t == T_ - 1) {
      hlast[(size_t)(g * 32 + r0) * 512 + (jb + uw)]      = hh0;
      hlast[(size_t)(g * 32 + r0 + 16) * 512 + (jb + uw)] = hh1;
    }
    // lane<32: one 8B write-through store (row = lane, 4 units contiguous)
    if (lane < 32) {
      int b16l = lane >> 4, bl = lane & 15;
      size_t off = (size_t)(L1 ? (t & 3) : t) * 131072
                 + (size_t)((g * 2 + b16l) * 16 + kcb) * 512 + (qq * 16 + bl) * 8 + jjb;
      u64 v = *(const u64*)(hst + lane * 4);
      AS64((u64*)(Hdst + off), v);
    }
    asm volatile("s_waitcnt vmcnt(0)" ::: "memory");   // h at LLC before barrier
    __syncthreads();                                   // whole WG's h committed
    if (tid == 0) AS32(fown + wgi * 32, (unsigned int)(t + 1));  // ONE flag/WG
    // hbuf WAR: next step's staging writes are gated by the fown>=t poll,
    // whose flags are stored only after this barrier => all hbuf reads done.
  }
}

__global__ __launch_bounds__(256, 2) void lstm_fused(
    const u16* __restrict__ Wp0, const float* __restrict__ bp0,
    const u16* __restrict__ Wp1, const float* __restrict__ bp1,
    const u16* __restrict__ Xsw, u16* __restrict__ Hrot0,
    u16* __restrict__ Hring, float* __restrict__ hlast,
    unsigned int* __restrict__ sync)
{
  __shared__ __align__(16) float gwb[4][640];   // per-wave gate transpose (stride 20)
  __shared__ u64 hstb[4][32];                   // per-wave h staging (256B)
  __shared__ u64 hbuf[4096];                    // layer1 h1 tile (32KB)
  __shared__ int eps_s;                         // per-WG step epoch (delegated poll)
  const int tid = threadIdx.x, lane = tid & 63, wave = tid >> 6;
  const int bid = blockIdx.x;
  if (tid == 0) eps_s = 0;
  __syncthreads();
  float* gw = gwb[wave];
  u16*  hst = (u16*)hstb[wave];
  // flag regions: 4KB per group-layer (32 WG flags x 128B)
  if (bid < 256) {
    const int g = bid & 7, widx = (bid >> 3) * 4 + wave;
    layer_loop<8, false, false>(Wp0, bp0, Xsw, Hrot0, nullptr,
                                sync + g * 1024, nullptr,
                                g, widx, lane, tid, wave, gw, hst, hbuf, &eps_s);
  } else {
    const int b2 = bid - 256;
    const int g = b2 & 7, widx = (b2 >> 3) * 4 + wave;
    layer_loop<16, true, true>(Wp1, bp1, Hrot0, Hring, hlast,
                               sync + 8192 + g * 1024, sync + g * 1024,
                               g, widx, lane, tid, wave, gw, hst, hbuf, &eps_s);
  }
}

// ---------------- final projection y = hlast @ Wlin^T + b ----------------
__global__ void final_k(const float* __restrict__ hlast, const float* __restrict__ Wlin,
                        const float* __restrict__ blin, float* __restrict__ out)
{
  int b = blockIdx.x;
  int l = threadIdx.x;  // 64
  float s = 0.f;
#pragma unroll
  for (int j = l; j < 512; j += 64) s += hlast[(size_t)b * 512 + j] * Wlin[j];
#pragma unroll
  for (int off = 32; off > 0; off >>= 1) s += __shfl_down(s, off);
  if (l == 0) out[b] = s + blin[0];
}

extern "C" void kernel_launch(void* const* d_in, const int* in_sizes, int n_in,
                              void* d_out, int out_size, void* d_ws, size_t ws_size,
                              hipStream_t stream) {
  (void)in_sizes; (void)n_in; (void)out_size; (void)ws_size;
  const float* X    = (const float*)d_in[0];
  const float* Wih0 = (const float*)d_in[1];
  const float* Whh0 = (const float*)d_in[2];
  const float* bih0 = (const float*)d_in[3];
  const float* bhh0 = (const float*)d_in[4];
  const float* Wih1 = (const float*)d_in[5];
  const float* Whh1 = (const float*)d_in[6];
  const float* bih1 = (const float*)d_in[7];
  const float* bhh1 = (const float*)d_in[8];
  const float* Wlin = (const float*)d_in[9];
  const float* blin = (const float*)d_in[10];
  float* out = (float*)d_out;

  char* ws = (char*)d_ws;
  size_t o = 0;
  auto take = [&](size_t bytes) { char* p = ws + o; o = (o + bytes + 255) & ~(size_t)255; return p; };
  u16*   Wp0   = (u16*)take(2048ull * 768 * 2);              // 3 MB
  u16*   Wp1   = (u16*)take(2048ull * 1024 * 2);             // 4 MB
  float* bp0   = (float*)take(2048 * 4);
  float* bp1   = (float*)take(2048 * 4);
  u16*   Xsw   = (u16*)take((size_t)B_ * T_ * 256 * 2);      // 67 MB
  u16*   Hrot0 = (u16*)take((size_t)T_ * B_ * 512 * 2);      // 134 MB (full-depth h0)
  u16*   Hring = (u16*)take((size_t)4 * B_ * 512 * 2);       // 1 MB (h1, depth 4)
  float* hlast = (float*)take((size_t)B_ * 512 * 4);         // 512 KB
  unsigned int* sync = (unsigned int*)take(65536);           // 2 layers x 8 groups x 32 flags x 128B

  hipMemsetAsync(sync, 0, 65536, stream);

  pack_w<8> <<<768,  256, 0, stream>>>(Wih0, Whh0, bih0, bhh0, Wp0, bp0);
  pack_w<16><<<1024, 256, 0, stream>>>(Wih1, Whh1, bih1, bhh1, Wp1, bp1);
  pack_x    <<<16384,256, 0, stream>>>(X, Xsw);

  lstm_fused<<<512, 256, 0, stream>>>(Wp0, bp0, Wp1, bp1, Xsw, Hrot0, Hring, hlast, sync);
  final_k<<<256, 64, 0, stream>>>(hlast, Wlin, blin, out);
}